// Round 9
// baseline (594.056 us; speedup 1.0000x reference)
//
#include <hip/hip_runtime.h>
#include <hip/hip_cooperative_groups.h>

namespace cg = cooperative_groups;

#define EDIM   4096
#define NHEAD  32
#define DHEAD  128
#define LCACHE 8191
#define LTOT   8192

// cooperative-kernel geometry (512 blocks)
#define CNBLK  512
#define CSPLIT 512
#define CRPB   16    // rows per split
#define CNGRP  16    // combine groups per head
#define CSPG   32    // splits per group

// fallback-pipeline geometry (R6, verified 167us)
#define FSPLIT 1024
#define FRPB   8
#define FNGRP  8
#define FSPG   128

#define SCALE 0.08838834764831845f  // 1/sqrt(128)

typedef float __attribute__((ext_vector_type(4))) f32x4;

__device__ __forceinline__ f32x4 ntload4(const float* p) {
    return __builtin_nontemporal_load((const f32x4*)p);
}
__device__ __forceinline__ void ntstore4(float* p, f32x4 v) {
    __builtin_nontemporal_store(v, (f32x4*)p);
}
__device__ __forceinline__ f32x4 ld4(const float* p) {
    return *(const f32x4*)p;
}
__device__ __forceinline__ float dot4(f32x4 a, f32x4 b) {
    return a.x*b.x + a.y*b.y + a.z*b.z + a.w*b.w;
}

// ===========================================================================
// Cooperative giant kernel: 512 blocks x 256 threads, 5 phases.
// ===========================================================================
__global__ __launch_bounds__(256, 2) void giant_kernel(
    const float* __restrict__ seq, const float* __restrict__ kc,
    const float* __restrict__ vc,  const float* __restrict__ Wq,
    const float* __restrict__ bq,  const float* __restrict__ Wk,
    const float* __restrict__ bk,  const float* __restrict__ Wv,
    const float* __restrict__ bv,  float* __restrict__ out,
    float* __restrict__ q_f, float* __restrict__ attn_f,
    float* __restrict__ pm, float* __restrict__ pl,
    float* __restrict__ gm, float* __restrict__ gl,
    float* __restrict__ go, float* __restrict__ po)
{
    cg::grid_group grid = cg::this_grid();
    const int t = threadIdx.x;
    float* knew = out + EDIM;
    float* vnew = out + (size_t)EDIM * (1 + LTOT);

    __shared__ float sm[CSPG], sw[CSPG];
    __shared__ f32x4 red[8][32];
    __shared__ float redl[8];

    // ============ Phase A: q/k/v GEMVs, 2 rows per wave ============
    {
        int lane = t & 63;
        int w0 = blockIdx.x * 8 + (t >> 6) * 2;
        const float* wq0 = Wq + (size_t)w0 * EDIM; const float* wq1 = wq0 + EDIM;
        const float* wk0 = Wk + (size_t)w0 * EDIM; const float* wk1 = wk0 + EDIM;
        const float* wv0 = Wv + (size_t)w0 * EDIM; const float* wv1 = wv0 + EDIM;
        float aq0 = 0.f, aq1 = 0.f, ak0 = 0.f, ak1 = 0.f, av0 = 0.f, av1 = 0.f;
#pragma unroll
        for (int i = 0; i < 16; ++i) {
            int c = (i * 64 + lane) * 4;
            f32x4 sv = ld4(seq + c);
            aq0 += dot4(ld4(wq0 + c), sv);      // temporal: reused in phase D
            aq1 += dot4(ld4(wq1 + c), sv);
            ak0 += dot4(ntload4(wk0 + c), sv);
            ak1 += dot4(ntload4(wk1 + c), sv);
            av0 += dot4(ntload4(wv0 + c), sv);
            av1 += dot4(ntload4(wv1 + c), sv);
        }
#pragma unroll
        for (int m = 32; m; m >>= 1) {
            aq0 += __shfl_xor(aq0, m); aq1 += __shfl_xor(aq1, m);
            ak0 += __shfl_xor(ak0, m); ak1 += __shfl_xor(ak1, m);
            av0 += __shfl_xor(av0, m); av1 += __shfl_xor(av1, m);
        }
        if (lane == 0) {
            q_f[w0]     = aq0 + bq[w0];
            q_f[w0 + 1] = aq1 + bq[w0 + 1];
            out[(size_t)EDIM * (1 + LCACHE) + w0]            = ak0 + bk[w0];
            out[(size_t)EDIM * (1 + LCACHE) + w0 + 1]        = ak1 + bk[w0 + 1];
            out[(size_t)EDIM * (1 + LTOT + LCACHE) + w0]     = av0 + bv[w0];
            out[(size_t)EDIM * (1 + LTOT + LCACHE) + w0 + 1] = av1 + bv[w0 + 1];
        }
    }
    __threadfence();
    grid.sync();

    // ============ Phase B: fused copy + flash-decode (16 rows) ============
    {
        int s  = blockIdx.x;
        int g  = t >> 5;                 // head sub-group 0..7
        int r0 = s * CRPB;
        int c0 = t * 4;

        float qr[16];
#pragma unroll
        for (int j = 0; j < 4; ++j) {
            f32x4 v = ld4(q_f + j * 1024 + c0);
            qr[j*4+0] = v.x * SCALE; qr[j*4+1] = v.y * SCALE;
            qr[j*4+2] = v.z * SCALE; qr[j*4+3] = v.w * SCALE;
        }

        float m[4], l[4];
        f32x4 acc[4];
#pragma unroll
        for (int j = 0; j < 4; ++j) {
            m[j] = -1e30f; l[j] = 0.f;
            acc[j] = (f32x4){0.f, 0.f, 0.f, 0.f};
        }

        f32x4 a[4];
        {
            const float* ksrc = kc + (size_t)r0 * EDIM;   // r0 <= 8176 < LCACHE
#pragma unroll
            for (int j = 0; j < 4; ++j) a[j] = ntload4(ksrc + j * 1024 + c0);
        }

        for (int i = 0; i < CRPB; ++i) {
            int row = r0 + i;
            bool cached = row < LCACHE;
            f32x4 b[4];
            if (cached) {
                const float* vsrc = vc + (size_t)row * EDIM;
#pragma unroll
                for (int j = 0; j < 4; ++j) b[j] = ntload4(vsrc + j * 1024 + c0);
                float* kd = knew + (size_t)row * EDIM;
#pragma unroll
                for (int j = 0; j < 4; ++j) ntstore4(kd + j * 1024 + c0, a[j]);
            } else {
                const float* vsrc = vnew + (size_t)row * EDIM;
#pragma unroll
                for (int j = 0; j < 4; ++j) b[j] = ld4(vsrc + j * 1024 + c0);
            }
            float pd[4];
#pragma unroll
            for (int j = 0; j < 4; ++j) pd[j] = dot4(a[j], ld4(&qr[j*4]));
#pragma unroll
            for (int msk = 1; msk <= 16; msk <<= 1) {
#pragma unroll
                for (int j = 0; j < 4; ++j) pd[j] += __shfl_xor(pd[j], msk);
            }
            f32x4 a2[4];
            if (i + 1 < CRPB) {
                int nrow = row + 1;
                if (nrow < LCACHE) {
                    const float* ksrc = kc + (size_t)nrow * EDIM;
#pragma unroll
                    for (int j = 0; j < 4; ++j) a2[j] = ntload4(ksrc + j * 1024 + c0);
                } else {
                    const float* ksrc = knew + (size_t)nrow * EDIM;
#pragma unroll
                    for (int j = 0; j < 4; ++j) a2[j] = ld4(ksrc + j * 1024 + c0);
                }
            }
            if (cached) {
                float* vd = vnew + (size_t)row * EDIM;
#pragma unroll
                for (int j = 0; j < 4; ++j) ntstore4(vd + j * 1024 + c0, b[j]);
            }
#pragma unroll
            for (int j = 0; j < 4; ++j) {
                float mn = fmaxf(m[j], pd[j]);
                float r  = __expf(m[j] - mn);
                float p  = __expf(pd[j] - mn);
                l[j] = l[j] * r + p;
                acc[j] = acc[j] * r + p * b[j];
                m[j] = mn;
            }
#pragma unroll
            for (int j = 0; j < 4; ++j) a[j] = a2[j];
        }

        int lane32 = t & 31;
        if (lane32 == 0) {
#pragma unroll
            for (int j = 0; j < 4; ++j) {
                int head = j * 8 + g;
                pm[(size_t)head * CSPLIT + s] = m[j];
                pl[(size_t)head * CSPLIT + s] = l[j];
            }
        }
#pragma unroll
        for (int j = 0; j < 4; ++j) {
            int head = j * 8 + g;
            *(f32x4*)(po + ((size_t)head * CSPLIT + s) * DHEAD + lane32 * 4) = acc[j];
        }
    }
    __threadfence();
    grid.sync();

    // ============ Phase C1: combine level 1 (512 units) ============
    {
        int h   = blockIdx.x >> 4;
        int grp = blockIdx.x & 15;
        int sg  = t >> 5;
        int ln  = t & 31;
        int sp0 = grp * CSPG;

        if (t < CSPG) {
            sm[t] = pm[(size_t)h * CSPLIT + sp0 + t];
            sw[t] = pl[(size_t)h * CSPLIT + sp0 + t];
        }
        __syncthreads();

        float M = -1e30f;
#pragma unroll
        for (int i = 0; i < CSPG; ++i) M = fmaxf(M, sm[i]);

        f32x4 o4 = (f32x4){0.f, 0.f, 0.f, 0.f};
        float L = 0.f;
#pragma unroll
        for (int i = sg; i < CSPG; i += 8) {
            float w = __expf(sm[i] - M);
            o4 += w * ld4(po + ((size_t)h * CSPLIT + sp0 + i) * DHEAD + ln * 4);
            L += w * sw[i];
        }
        red[sg][ln] = o4;
        if (ln == 0) redl[sg] = L;
        __syncthreads();
        if (sg == 0) {
            f32x4 oo = red[0][ln];
#pragma unroll
            for (int k = 1; k < 8; ++k) oo += red[k][ln];
            *(f32x4*)(go + ((size_t)h * CNGRP + grp) * DHEAD + ln * 4) = oo;
            if (ln == 0) {
                float LL = redl[0];
#pragma unroll
                for (int k = 1; k < 8; ++k) LL += redl[k];
                gm[h * CNGRP + grp] = M;
                gl[h * CNGRP + grp] = LL;
            }
        }
    }
    __threadfence();
    grid.sync();

    // ============ Phase C2: combine level 2 (32 heads) ============
    if (blockIdx.x < NHEAD && t < DHEAD) {
        int h = blockIdx.x;
        int d = t;
        float M = -1e30f;
#pragma unroll
        for (int g = 0; g < CNGRP; ++g) M = fmaxf(M, gm[h * CNGRP + g]);
        float o = 0.f, L = 0.f;
#pragma unroll
        for (int g = 0; g < CNGRP; ++g) {
            float w = __expf(gm[h * CNGRP + g] - M);
            o += w * go[((size_t)h * CNGRP + g) * DHEAD + d];
            L += w * gl[h * CNGRP + g];
        }
        attn_f[h * DHEAD + d] = o / L;
    }
    __threadfence();
    grid.sync();

    // ============ Phase D: output projection, 2 rows per wave ============
    {
        int lane = t & 63;
        int w0 = blockIdx.x * 8 + (t >> 6) * 2;
        const float* wr0 = Wq + (size_t)w0 * EDIM;
        const float* wr1 = wr0 + EDIM;
        float s0 = 0.f, s1 = 0.f;
#pragma unroll
        for (int i = 0; i < 16; ++i) {
            int c = (i * 64 + lane) * 4;
            f32x4 av = ld4(attn_f + c);
            s0 += dot4(ld4(wr0 + c), av);
            s1 += dot4(ld4(wr1 + c), av);
        }
#pragma unroll
        for (int m = 32; m; m >>= 1) {
            s0 += __shfl_xor(s0, m); s1 += __shfl_xor(s1, m);
        }
        if (lane == 0) {
            out[w0]     = s0 + bq[w0];
            out[w0 + 1] = s1 + bq[w0 + 1];
        }
    }
}

// ===========================================================================
// Fallback pipeline (R6-verified kernels)
// ===========================================================================
__global__ __launch_bounds__(256) void fb_qkv(
    const float* __restrict__ seq,
    const float* __restrict__ Wq, const float* __restrict__ bq,
    const float* __restrict__ Wk, const float* __restrict__ bk,
    const float* __restrict__ Wv, const float* __restrict__ bv,
    float* __restrict__ q_f, float* __restrict__ out)
{
    int idx  = blockIdx.x * 4 + (threadIdx.x >> 6);
    int lane = threadIdx.x & 63;
    int sel  = idx >> 12;
    int row  = idx & 4095;
    const float* W = sel == 0 ? Wq : (sel == 1 ? Wk : Wv);
    const float* b = sel == 0 ? bq : (sel == 1 ? bk : bv);
    const float* wr = W + (size_t)row * EDIM;

    float sum = 0.f;
#pragma unroll
    for (int i = 0; i < 16; ++i) {
        int c = (i * 64 + lane) * 4;
        f32x4 w = (sel == 0) ? ld4(wr + c) : ntload4(wr + c);
        f32x4 s = ld4(seq + c);
        sum += dot4(w, s);
    }
#pragma unroll
    for (int m = 32; m; m >>= 1) sum += __shfl_xor(sum, m);
    if (lane == 0) {
        float total = sum + b[row];
        if (sel == 0)      q_f[row] = total;
        else if (sel == 1) out[(size_t)EDIM * (1 + LCACHE) + row] = total;
        else               out[(size_t)EDIM * (1 + LTOT + LCACHE) + row] = total;
    }
}

__global__ __launch_bounds__(256) void fb_fused(
    const float* __restrict__ kc, const float* __restrict__ vc,
    const float* __restrict__ q_f, float* __restrict__ out,
    float* __restrict__ pm, float* __restrict__ pl, float* __restrict__ po)
{
    int s  = blockIdx.x;
    int t  = threadIdx.x;
    int g  = t >> 5;
    int r0 = s * FRPB;

    float* knew = out + EDIM;
    float* vnew = out + (size_t)EDIM * (1 + LTOT);
    int c0 = t * 4;

    float qr[16];
#pragma unroll
    for (int j = 0; j < 4; ++j) {
        f32x4 v = ld4(q_f + j * 1024 + c0);
        qr[j*4+0] = v.x * SCALE; qr[j*4+1] = v.y * SCALE;
        qr[j*4+2] = v.z * SCALE; qr[j*4+3] = v.w * SCALE;
    }

    float m[4], l[4];
    f32x4 acc[4];
#pragma unroll
    for (int j = 0; j < 4; ++j) {
        m[j] = -1e30f; l[j] = 0.f;
        acc[j] = (f32x4){0.f, 0.f, 0.f, 0.f};
    }

    f32x4 a[4], b[4];
    {
        const float* ksrc = (r0 < LCACHE) ? (kc + (size_t)r0 * EDIM)
                                          : (knew + (size_t)r0 * EDIM);
        const float* vsrc = (r0 < LCACHE) ? (vc + (size_t)r0 * EDIM)
                                          : (vnew + (size_t)r0 * EDIM);
#pragma unroll
        for (int j = 0; j < 4; ++j) a[j] = ntload4(ksrc + j * 1024 + c0);
#pragma unroll
        for (int j = 0; j < 4; ++j) b[j] = ntload4(vsrc + j * 1024 + c0);
    }

    for (int i = 0; i < FRPB; ++i) {
        int row = r0 + i;
        f32x4 a2[4], b2[4];
        if (i + 1 < FRPB) {
            int nrow = row + 1;
            const float* ksrc = (nrow < LCACHE) ? (kc + (size_t)nrow * EDIM)
                                                : (knew + (size_t)nrow * EDIM);
            const float* vsrc = (nrow < LCACHE) ? (vc + (size_t)nrow * EDIM)
                                                : (vnew + (size_t)nrow * EDIM);
#pragma unroll
            for (int j = 0; j < 4; ++j) a2[j] = ntload4(ksrc + j * 1024 + c0);
#pragma unroll
            for (int j = 0; j < 4; ++j) b2[j] = ntload4(vsrc + j * 1024 + c0);
        }
        if (row < LCACHE) {
            float* kd = knew + (size_t)row * EDIM;
            float* vd = vnew + (size_t)row * EDIM;
#pragma unroll
            for (int j = 0; j < 4; ++j) ntstore4(kd + j * 1024 + c0, a[j]);
#pragma unroll
            for (int j = 0; j < 4; ++j) ntstore4(vd + j * 1024 + c0, b[j]);
        }
        float pd[4];
#pragma unroll
        for (int j = 0; j < 4; ++j) pd[j] = dot4(a[j], ld4(&qr[j*4]));
#pragma unroll
        for (int msk = 1; msk <= 16; msk <<= 1) {
#pragma unroll
            for (int j = 0; j < 4; ++j) pd[j] += __shfl_xor(pd[j], msk);
        }
#pragma unroll
        for (int j = 0; j < 4; ++j) {
            float mn = fmaxf(m[j], pd[j]);
            float r  = __expf(m[j] - mn);
            float p  = __expf(pd[j] - mn);
            l[j] = l[j] * r + p;
            acc[j] = acc[j] * r + p * b[j];
            m[j] = mn;
        }
#pragma unroll
        for (int j = 0; j < 4; ++j) { a[j] = a2[j]; b[j] = b2[j]; }
    }

    int lane32 = t & 31;
    if (lane32 == 0) {
#pragma unroll
        for (int j = 0; j < 4; ++j) {
            int head = j * 8 + g;
            pm[(size_t)head * FSPLIT + s] = m[j];
            pl[(size_t)head * FSPLIT + s] = l[j];
        }
    }
#pragma unroll
    for (int j = 0; j < 4; ++j) {
        int head = j * 8 + g;
        *(f32x4*)(po + ((size_t)head * FSPLIT + s) * DHEAD + lane32 * 4) = acc[j];
    }
}

__global__ __launch_bounds__(256) void fb_c1(
    const float* __restrict__ pm, const float* __restrict__ pl,
    const float* __restrict__ po,
    float* __restrict__ gm, float* __restrict__ gl, float* __restrict__ go)
{
    int h   = blockIdx.x;
    int grp = blockIdx.y;
    int t   = threadIdx.x;
    int sg  = t >> 5;
    int ln  = t & 31;
    int s0  = grp * FSPG;

    __shared__ float sm[FSPG], sw[FSPG];
    __shared__ f32x4 red[8][32];
    __shared__ float redl[8];

    if (t < FSPG) {
        sm[t] = pm[(size_t)h * FSPLIT + s0 + t];
        sw[t] = pl[(size_t)h * FSPLIT + s0 + t];
    }
    __syncthreads();

    float M = -1e30f;
#pragma unroll 8
    for (int i = 0; i < FSPG; ++i) M = fmaxf(M, sm[i]);

    f32x4 o4 = (f32x4){0.f, 0.f, 0.f, 0.f};
    float L = 0.f;
    for (int i = sg; i < FSPG; i += 8) {
        float w = __expf(sm[i] - M);
        o4 += w * ld4(po + ((size_t)h * FSPLIT + s0 + i) * DHEAD + ln * 4);
        L += w * sw[i];
    }
    red[sg][ln] = o4;
    if (ln == 0) redl[sg] = L;
    __syncthreads();
    if (sg == 0) {
        f32x4 oo = red[0][ln];
#pragma unroll
        for (int k = 1; k < 8; ++k) oo += red[k][ln];
        *(f32x4*)(go + ((size_t)h * FNGRP + grp) * DHEAD + ln * 4) = oo;
        if (ln == 0) {
            float LL = redl[0];
#pragma unroll
            for (int k = 1; k < 8; ++k) LL += redl[k];
            gm[h * FNGRP + grp] = M;
            gl[h * FNGRP + grp] = LL;
        }
    }
}

__global__ __launch_bounds__(128) void fb_c2(
    const float* __restrict__ gm, const float* __restrict__ gl,
    const float* __restrict__ go, float* __restrict__ attn_f)
{
    int h = blockIdx.x;
    int d = threadIdx.x;
    float M = -1e30f;
#pragma unroll
    for (int g = 0; g < FNGRP; ++g) M = fmaxf(M, gm[h * FNGRP + g]);
    float o = 0.f, L = 0.f;
#pragma unroll
    for (int g = 0; g < FNGRP; ++g) {
        float w = __expf(gm[h * FNGRP + g] - M);
        o += w * go[((size_t)h * FNGRP + g) * DHEAD + d];
        L += w * gl[h * FNGRP + g];
    }
    attn_f[h * DHEAD + d] = o / L;
}

__global__ __launch_bounds__(256) void fb_proj(
    const float* __restrict__ attn_f, const float* __restrict__ Wq,
    const float* __restrict__ bq, float* __restrict__ out)
{
    int row  = blockIdx.x * 4 + (threadIdx.x >> 6);
    int lane = threadIdx.x & 63;
    const float* wr = Wq + (size_t)row * EDIM;

    float sum = 0.f;
#pragma unroll
    for (int i = 0; i < 16; ++i) {
        int c = (i * 64 + lane) * 4;
        sum += dot4(ld4(wr + c), ld4(attn_f + c));
    }
#pragma unroll
    for (int m = 32; m; m >>= 1) sum += __shfl_xor(sum, m);
    if (lane == 0)
        out[row] = sum + bq[row];
}

// ---------------------------------------------------------------------------
extern "C" void kernel_launch(void* const* d_in, const int* in_sizes, int n_in,
                              void* d_out, int out_size, void* d_ws, size_t ws_size,
                              hipStream_t stream)
{
    const float* seq = (const float*)d_in[0];
    const float* kc  = (const float*)d_in[1];
    const float* vc  = (const float*)d_in[2];
    const float* Wq  = (const float*)d_in[3];
    const float* bq  = (const float*)d_in[4];
    const float* Wk  = (const float*)d_in[5];
    const float* bk  = (const float*)d_in[6];
    const float* Wv  = (const float*)d_in[7];
    const float* bv  = (const float*)d_in[8];
    float* out = (float*)d_out;

    float* wsf    = (float*)d_ws;
    float* q_f    = wsf;                         // 4096
    float* attn_f = wsf + 4096;                  // 4096
    float* pm     = wsf + 8192;                  // 32*1024 (max of both paths)
    float* pl     = pm + NHEAD * 1024;
    float* gm     = pl + NHEAD * 1024;           // 32*32 max
    float* gl     = gm + NHEAD * 32;
    float* go     = gl + NHEAD * 32;             // 32*32*128 max
    float* po     = go + NHEAD * 32 * DHEAD;     // 32*1024*128 max

    void* args[] = {
        (void*)&seq, (void*)&kc, (void*)&vc, (void*)&Wq, (void*)&bq,
        (void*)&Wk, (void*)&bk, (void*)&Wv, (void*)&bv, (void*)&out,
        (void*)&q_f, (void*)&attn_f, (void*)&pm, (void*)&pl,
        (void*)&gm, (void*)&gl, (void*)&go, (void*)&po
    };
    hipError_t err = hipLaunchCooperativeKernel(
        (const void*)giant_kernel, dim3(CNBLK), dim3(256), args, 0, stream);

    if (err != hipSuccess) {
        // fallback: verified 5-kernel pipeline (R6)
        hipLaunchKernelGGL(fb_qkv, dim3(3072), dim3(256), 0, stream,
                           seq, Wq, bq, Wk, bk, Wv, bv, q_f, out);
        hipLaunchKernelGGL(fb_fused, dim3(FSPLIT), dim3(256), 0, stream,
                           kc, vc, q_f, out, pm, pl, po);
        hipLaunchKernelGGL(fb_c1, dim3(NHEAD, FNGRP), dim3(256), 0, stream,
                           pm, pl, po, gm, gl, go);
        hipLaunchKernelGGL(fb_c2, dim3(NHEAD), dim3(128), 0, stream,
                           gm, gl, go, attn_f);
        hipLaunchKernelGGL(fb_proj, dim3(1024), dim3(256), 0, stream,
                           attn_f, Wq, bq, out);
    }
}

// Round 11
// 171.252 us; speedup vs baseline: 3.4689x; 3.4689x over previous
//
#include <hip/hip_runtime.h>

#define EDIM   4096
#define NHEAD  32
#define DHEAD  128
#define LCACHE 8191
#define LTOT   8192
#define NSPLIT 1024
#define RPB    8     // rows per split (NSPLIT*RPB == LTOT)
#define NGRP   8     // combine stage-1 groups
#define SPG    128   // splits per group (NSPLIT/NGRP)

#define SCALE 0.08838834764831845f  // 1/sqrt(128)

typedef float __attribute__((ext_vector_type(4))) f32x4;
typedef unsigned short u16;
typedef unsigned short __attribute__((ext_vector_type(4))) u16x4;

__device__ __forceinline__ f32x4 ntload4(const float* p) {
    return __builtin_nontemporal_load((const f32x4*)p);
}
__device__ __forceinline__ void ntstore4(float* p, f32x4 v) {
    __builtin_nontemporal_store(v, (f32x4*)p);
}
__device__ __forceinline__ f32x4 ld4(const float* p) {
    return *(const f32x4*)p;
}
__device__ __forceinline__ float dot4(f32x4 a, f32x4 b) {
    return a.x*b.x + a.y*b.y + a.z*b.z + a.w*b.w;
}
__device__ __forceinline__ u16 f2bf(float f) {
    union { float f; unsigned int u; } x; x.f = f;
    unsigned int r = x.u + 0x7fffu + ((x.u >> 16) & 1u);  // RNE
    return (u16)(r >> 16);
}
__device__ __forceinline__ float bf2f(u16 u) {
    union { unsigned int u; float f; } x;
    x.u = ((unsigned int)u) << 16;
    return x.f;
}

// ---------------------------------------------------------------------------
// Kernel 1: q/k/v GEMVs. One 64-lane wave per output row, 4 rows/block.
// grid 3072. Wk/Wv non-temporal (read-once); Wq temporal (reused by proj).
// ---------------------------------------------------------------------------
__global__ __launch_bounds__(256) void qkv_kernel(
    const float* __restrict__ seq,
    const float* __restrict__ Wq, const float* __restrict__ bq,
    const float* __restrict__ Wk, const float* __restrict__ bk,
    const float* __restrict__ Wv, const float* __restrict__ bv,
    float* __restrict__ q_f, float* __restrict__ out)
{
    int idx  = blockIdx.x * 4 + (threadIdx.x >> 6);
    int lane = threadIdx.x & 63;
    int sel  = idx >> 12;
    int row  = idx & 4095;
    const float* W = sel == 0 ? Wq : (sel == 1 ? Wk : Wv);
    const float* b = sel == 0 ? bq : (sel == 1 ? bk : bv);
    const float* wr = W + (size_t)row * EDIM;

    float sum = 0.f;
#pragma unroll
    for (int i = 0; i < 16; ++i) {
        int c = (i * 64 + lane) * 4;
        f32x4 w = (sel == 0) ? ld4(wr + c) : ntload4(wr + c);
        f32x4 s = ld4(seq + c);
        sum += dot4(w, s);
    }
#pragma unroll
    for (int m = 32; m; m >>= 1) sum += __shfl_xor(sum, m);
    if (lane == 0) {
        float total = sum + b[row];
        if (sel == 0)      q_f[row] = total;
        else if (sel == 1) out[(size_t)EDIM * (1 + LCACHE) + row] = total;
        else               out[(size_t)EDIM * (1 + LTOT + LCACHE) + row] = total;
    }
}

// ---------------------------------------------------------------------------
// Kernel 2: fused KV-copy + flash-decode, one-pass online softmax.
// grid 1024, block 256 (launch_bounds (256,4) -> VGPR<=128, 4 blocks/CU).
// Thread t chunk j owns elements (j*256+t)*4.. -> head j*8+(t>>5).
// 2-deep register prefetch of both K and V rows; NT everywhere; no barriers.
// po partials stored bf16 (halves po traffic).
// ---------------------------------------------------------------------------
__global__ __launch_bounds__(256, 4) void fused_kernel(
    const float* __restrict__ kc, const float* __restrict__ vc,
    const float* __restrict__ q_f, float* __restrict__ out,
    float* __restrict__ pm, float* __restrict__ pl, u16* __restrict__ po)
{
    int s  = blockIdx.x;
    int t  = threadIdx.x;
    int g  = t >> 5;
    int r0 = s * RPB;

    float* knew = out + EDIM;
    float* vnew = out + (size_t)EDIM * (1 + LTOT);
    int c0 = t * 4;

    float qr[16];
#pragma unroll
    for (int j = 0; j < 4; ++j) {
        f32x4 v = ld4(q_f + j * 1024 + c0);
        qr[j*4+0] = v.x * SCALE; qr[j*4+1] = v.y * SCALE;
        qr[j*4+2] = v.z * SCALE; qr[j*4+3] = v.w * SCALE;
    }

    float m[4], l[4];
    f32x4 acc[4];
#pragma unroll
    for (int j = 0; j < 4; ++j) {
        m[j] = -1e30f; l[j] = 0.f;
        acc[j] = (f32x4){0.f, 0.f, 0.f, 0.f};
    }

    f32x4 a[4], b[4];
    {
        const float* ksrc = (r0 < LCACHE) ? (kc + (size_t)r0 * EDIM)
                                          : (knew + (size_t)r0 * EDIM);
        const float* vsrc = (r0 < LCACHE) ? (vc + (size_t)r0 * EDIM)
                                          : (vnew + (size_t)r0 * EDIM);
#pragma unroll
        for (int j = 0; j < 4; ++j) a[j] = ntload4(ksrc + j * 1024 + c0);
#pragma unroll
        for (int j = 0; j < 4; ++j) b[j] = ntload4(vsrc + j * 1024 + c0);
    }

    for (int i = 0; i < RPB; ++i) {
        int row = r0 + i;
        f32x4 a2[4], b2[4];
        if (i + 1 < RPB) {
            int nrow = row + 1;
            const float* ksrc = (nrow < LCACHE) ? (kc + (size_t)nrow * EDIM)
                                                : (knew + (size_t)nrow * EDIM);
            const float* vsrc = (nrow < LCACHE) ? (vc + (size_t)nrow * EDIM)
                                                : (vnew + (size_t)nrow * EDIM);
#pragma unroll
            for (int j = 0; j < 4; ++j) a2[j] = ntload4(ksrc + j * 1024 + c0);
#pragma unroll
            for (int j = 0; j < 4; ++j) b2[j] = ntload4(vsrc + j * 1024 + c0);
        }
        if (row < LCACHE) {
            float* kd = knew + (size_t)row * EDIM;
            float* vd = vnew + (size_t)row * EDIM;
#pragma unroll
            for (int j = 0; j < 4; ++j) ntstore4(kd + j * 1024 + c0, a[j]);
#pragma unroll
            for (int j = 0; j < 4; ++j) ntstore4(vd + j * 1024 + c0, b[j]);
        }
        float pd[4];
#pragma unroll
        for (int j = 0; j < 4; ++j) pd[j] = dot4(a[j], ld4(&qr[j*4]));
#pragma unroll
        for (int msk = 1; msk <= 16; msk <<= 1) {
#pragma unroll
            for (int j = 0; j < 4; ++j) pd[j] += __shfl_xor(pd[j], msk);
        }
#pragma unroll
        for (int j = 0; j < 4; ++j) {
            float mn = fmaxf(m[j], pd[j]);
            float r  = __expf(m[j] - mn);
            float p  = __expf(pd[j] - mn);
            l[j] = l[j] * r + p;
            acc[j] = acc[j] * r + p * b[j];
            m[j] = mn;
        }
#pragma unroll
        for (int j = 0; j < 4; ++j) { a[j] = a2[j]; b[j] = b2[j]; }
    }

    int lane32 = t & 31;
    if (lane32 == 0) {
#pragma unroll
        for (int j = 0; j < 4; ++j) {
            int head = j * 8 + g;
            pm[(size_t)head * NSPLIT + s] = m[j];
            pl[(size_t)head * NSPLIT + s] = l[j];
        }
    }
#pragma unroll
    for (int j = 0; j < 4; ++j) {
        int head = j * 8 + g;
        u16x4 pk;
        pk.x = f2bf(acc[j].x); pk.y = f2bf(acc[j].y);
        pk.z = f2bf(acc[j].z); pk.w = f2bf(acc[j].w);
        __builtin_nontemporal_store(pk,
            (u16x4*)(po + ((size_t)head * NSPLIT + s) * DHEAD + lane32 * 4));
    }
}

// ---------------------------------------------------------------------------
// Kernel 3: combine stage 1.  grid (NHEAD, NGRP), 256 thr = 8 subgroups
// of 32 lanes; lane owns 4 dims (bf16x4 po reads); subgroup strides splits.
// ---------------------------------------------------------------------------
__global__ __launch_bounds__(256) void combine1_kernel(
    const float* __restrict__ pm, const float* __restrict__ pl,
    const u16* __restrict__ po,
    float* __restrict__ gm, float* __restrict__ gl, float* __restrict__ go)
{
    int h   = blockIdx.x;
    int grp = blockIdx.y;
    int t   = threadIdx.x;
    int sg  = t >> 5;
    int ln  = t & 31;
    int s0  = grp * SPG;

    __shared__ float sm[SPG], sw[SPG];
    __shared__ f32x4 red[8][32];
    __shared__ float redl[8];

    if (t < SPG) {
        sm[t] = pm[(size_t)h * NSPLIT + s0 + t];
        sw[t] = pl[(size_t)h * NSPLIT + s0 + t];
    }
    __syncthreads();

    float M = -1e30f;
#pragma unroll 8
    for (int i = 0; i < SPG; ++i) M = fmaxf(M, sm[i]);

    f32x4 o4 = (f32x4){0.f, 0.f, 0.f, 0.f};
    float L = 0.f;
    for (int i = sg; i < SPG; i += 8) {
        float w = __expf(sm[i] - M);
        u16x4 u = *(const u16x4*)(po + ((size_t)h * NSPLIT + s0 + i) * DHEAD + ln * 4);
        f32x4 v;
        v.x = bf2f(u.x); v.y = bf2f(u.y); v.z = bf2f(u.z); v.w = bf2f(u.w);
        o4 += w * v;
        L += w * sw[i];
    }
    red[sg][ln] = o4;
    if (ln == 0) redl[sg] = L;
    __syncthreads();
    if (sg == 0) {
        f32x4 oo = red[0][ln];
#pragma unroll
        for (int k = 1; k < 8; ++k) oo += red[k][ln];
        *(f32x4*)(go + ((size_t)h * NGRP + grp) * DHEAD + ln * 4) = oo;
        if (ln == 0) {
            float LL = redl[0];
#pragma unroll
            for (int k = 1; k < 8; ++k) LL += redl[k];
            gm[h * NGRP + grp] = M;
            gl[h * NGRP + grp] = LL;
        }
    }
}

// ---------------------------------------------------------------------------
// Kernel 4: combine stage 2.  grid NHEAD, 128 thr: merge NGRP groups.
// ---------------------------------------------------------------------------
__global__ __launch_bounds__(128) void combine2_kernel(
    const float* __restrict__ gm, const float* __restrict__ gl,
    const float* __restrict__ go, float* __restrict__ attn_f)
{
    int h = blockIdx.x;
    int d = threadIdx.x;
    float M = -1e30f;
#pragma unroll
    for (int g = 0; g < NGRP; ++g) M = fmaxf(M, gm[h * NGRP + g]);
    float o = 0.f, L = 0.f;
#pragma unroll
    for (int g = 0; g < NGRP; ++g) {
        float w = __expf(gm[h * NGRP + g] - M);
        o += w * go[((size_t)h * NGRP + g) * DHEAD + d];
        L += w * gl[h * NGRP + g];
    }
    attn_f[h * DHEAD + d] = o / L;
}

// ---------------------------------------------------------------------------
// Kernel 5: output projection. One wave per row, 4 rows/block, grid 1024.
// ---------------------------------------------------------------------------
__global__ __launch_bounds__(256) void proj_kernel(
    const float* __restrict__ attn_f, const float* __restrict__ Wq,
    const float* __restrict__ bq, float* __restrict__ out)
{
    int row  = blockIdx.x * 4 + (threadIdx.x >> 6);
    int lane = threadIdx.x & 63;
    const float* wr = Wq + (size_t)row * EDIM;

    float sum = 0.f;
#pragma unroll
    for (int i = 0; i < 16; ++i) {
        int c = (i * 64 + lane) * 4;
        sum += dot4(ld4(wr + c), ld4(attn_f + c));
    }
#pragma unroll
    for (int m = 32; m; m >>= 1) sum += __shfl_xor(sum, m);
    if (lane == 0)
        out[row] = sum + bq[row];
}

// ---------------------------------------------------------------------------
extern "C" void kernel_launch(void* const* d_in, const int* in_sizes, int n_in,
                              void* d_out, int out_size, void* d_ws, size_t ws_size,
                              hipStream_t stream)
{
    const float* seq = (const float*)d_in[0];
    const float* kc  = (const float*)d_in[1];
    const float* vc  = (const float*)d_in[2];
    const float* Wq  = (const float*)d_in[3];
    const float* bq  = (const float*)d_in[4];
    const float* Wk  = (const float*)d_in[5];
    const float* bk  = (const float*)d_in[6];
    const float* Wv  = (const float*)d_in[7];
    const float* bv  = (const float*)d_in[8];
    float* out = (float*)d_out;

    float* wsf    = (float*)d_ws;
    float* q_f    = wsf;                        // 4096
    float* attn_f = wsf + 4096;                 // 4096
    float* pm     = wsf + 8192;                 // 32*1024
    float* pl     = pm + NHEAD * NSPLIT;        // 32*1024
    float* gm     = pl + NHEAD * NSPLIT;        // 32*8
    float* gl     = gm + NHEAD * NGRP;          // 32*8
    float* go     = gl + NHEAD * NGRP;          // 32*8*128
    u16*   po     = (u16*)(go + NHEAD * NGRP * DHEAD);  // 32*1024*128 bf16

    hipLaunchKernelGGL(qkv_kernel, dim3(3072), dim3(256), 0, stream,
                       seq, Wq, bq, Wk, bk, Wv, bv, q_f, out);
    hipLaunchKernelGGL(fused_kernel, dim3(NSPLIT), dim3(256), 0, stream,
                       kc, vc, q_f, out, pm, pl, po);
    hipLaunchKernelGGL(combine1_kernel, dim3(NHEAD, NGRP), dim3(256), 0, stream,
                       pm, pl, po, gm, gl, go);
    hipLaunchKernelGGL(combine2_kernel, dim3(NHEAD), dim3(128), 0, stream,
                       gm, gl, go, attn_f);
    hipLaunchKernelGGL(proj_kernel, dim3(1024), dim3(256), 0, stream,
                       attn_f, Wq, bq, out);
}